// Round 14
// baseline (597.893 us; speedup 1.0000x reference)
//
#include <hip/hip_runtime.h>
#include <stdint.h>

typedef short short8 __attribute__((ext_vector_type(8)));
typedef float f32x4 __attribute__((ext_vector_type(4)));

#define D 128
#define LOG2E 1.44269504088896340736f

__device__ __forceinline__ unsigned short f2bf(float f) {
    union { float f; unsigned u; } v; v.f = f;
    unsigned u = v.u;
    unsigned r = (u + 0x7FFFu + ((u >> 16) & 1u)) >> 16;  // RNE
    return (unsigned short)r;
}

// pack two f32 -> one u32 of two bf16 (round-half-up via +0x8000, then v_perm)
__device__ __forceinline__ unsigned packbf(float x, float y) {
    unsigned ux = __float_as_uint(x) + 0x8000u;
    unsigned uy = __float_as_uint(y) + 0x8000u;
    return __builtin_amdgcn_perm(uy, ux, 0x07060302u);
}

// HBM -> LDS direct (16B per lane). LDS dest must be linear base + lane*16.
__device__ __forceinline__ void gld16(const float* g, float* l) {
    __builtin_amdgcn_global_load_lds(
        (const __attribute__((address_space(1))) void*)g,
        (__attribute__((address_space(3))) void*)l, 16, 0, 0);
}

// ---------------------------------------------------------------------------
// Kernel 1: pre-pack (Wu * log2e) as bf16 MFMA fragments (A/B layout is
// lane-identical): t = nt*256 + kk*64 + lane holds
// Wu[nt*16+(lane&15)][kk*32+(lane>>4)*8+j] * log2e.
// ---------------------------------------------------------------------------
__global__ __launch_bounds__(256) void pack_wu(const float* __restrict__ Wu,
                                               short8* __restrict__ frag) {
    int tid = blockIdx.x * 256 + threadIdx.x;
    int nt = tid >> 8, kk = (tid >> 6) & 3, l = tid & 63;
    int col = nt * 16 + (l & 15);
    int kb  = kk * 32 + ((l >> 4) * 8);
    short8 o;
#pragma unroll
    for (int j = 0; j < 8; ++j) o[j] = (short)f2bf(Wu[col * D + kb + j] * LOG2E);
    frag[tid] = o;
}

// ---------------------------------------------------------------------------
// Kernel 2: per-graph gate factors  c = 2^{-(Wv·x_last + bu)·log2e}. (verified)
// ---------------------------------------------------------------------------
__global__ __launch_bounds__(256) void gate_k(const float* __restrict__ xI,
                                              const float* __restrict__ xV,
                                              const float* __restrict__ Wv,
                                              const float* __restrict__ bu,
                                              const int* __restrict__ lastn,
                                              float* __restrict__ cIb,
                                              float* __restrict__ cVb, int B) {
    __shared__ __align__(16) float xs[4][2][D];
    int t = threadIdx.x, h = t & 127, st = t >> 7;
    float bias = bu[h];
    const float4* wv4 = (const float4*)(Wv + (size_t)h * D);
    const float* src = st ? xV : xI;
    float* dst = st ? cVb : cIb;
    int g0 = blockIdx.x * 16;
    for (int p = 0; p < 4; ++p) {
        int gb = g0 + p * 4;
#pragma unroll
        for (int j = 0; j < 4; ++j) {
            int gg = gb + j; if (gg >= B) gg = B - 1;
            xs[j][st][h] = src[(size_t)lastn[gg] * D + h];
        }
        __syncthreads();
        const float4* x0 = (const float4*)xs[0][st];
        const float4* x1 = (const float4*)xs[1][st];
        const float4* x2 = (const float4*)xs[2][st];
        const float4* x3 = (const float4*)xs[3][st];
        float a0 = 0.f, a1 = 0.f, a2 = 0.f, a3 = 0.f;
#pragma unroll
        for (int i = 0; i < 32; ++i) {
            float4 w = wv4[i], b;
            b = x0[i]; a0 += w.x*b.x + w.y*b.y + w.z*b.z + w.w*b.w;
            b = x1[i]; a1 += w.x*b.x + w.y*b.y + w.z*b.z + w.w*b.w;
            b = x2[i]; a2 += w.x*b.x + w.y*b.y + w.z*b.z + w.w*b.w;
            b = x3[i]; a3 += w.x*b.x + w.y*b.y + w.z*b.z + w.w*b.w;
        }
        if (gb + 0 < B) dst[(size_t)(gb+0)*D + h] = __builtin_amdgcn_exp2f(-(a0+bias)*LOG2E);
        if (gb + 1 < B) dst[(size_t)(gb+1)*D + h] = __builtin_amdgcn_exp2f(-(a1+bias)*LOG2E);
        if (gb + 2 < B) dst[(size_t)(gb+2)*D + h] = __builtin_amdgcn_exp2f(-(a2+bias)*LOG2E);
        if (gb + 3 < B) dst[(size_t)(gb+3)*D + h] = __builtin_amdgcn_exp2f(-(a3+bias)*LOG2E);
        __syncthreads();
    }
}

// ---------------------------------------------------------------------------
// Kernel 3: fused main = gld16 staging pipeline (r4) x wu-in-VGPR swapped
// MFMA (r13). Block per graph, 4 waves striding 16-row chunks. No LDS bfrag
// (Wu lives in 64 statically-indexed VGPRs/wave); rows staged HBM->LDS via
// global_load_lds (zero gather VGPRs, pre-swizzled source); per chunk:
//   vmcnt(0) -> af (swizzled b128) + fr (float2) from LDS -> lgkmcnt(0) ->
//   issue next chunk's gld16 (hidden under compute) -> swapped MFMA ->
//   scalar-e epilogue -> weights 2^e (no max, r9 bound) -> accumulate.
// LDS ~38.5 KB -> 4 blocks/CU; launch_bounds(256,3) caps VGPR at ~170
// (above need -> no spill throttling).
// ---------------------------------------------------------------------------
__global__ __launch_bounds__(256, 3) void attn_main(
    const float* __restrict__ xI, const float* __restrict__ xV,
    const float* __restrict__ We, const int* __restrict__ lastn,
    const float* __restrict__ cIb, const float* __restrict__ cVb,
    const short8* __restrict__ fragG, float* __restrict__ out, int B) {
    __shared__ __align__(16) float stage[4][2048];   // 32 KB row staging
    __shared__ __align__(16) float gl[3][D];         // We*log2e, cI, cV
    __shared__ __align__(16) float wt[4][16][2];     // per-wave weights
    __shared__ float cmbA[2][4][D];                  // combine (plain sums)
    __shared__ float cmbL[2][4];

    int t = threadIdx.x, lane = t & 63, w = t >> 6;
    int g = blockIdx.x;

    // Wu fragments -> 64 VGPRs (statically indexed; L2-hot for all blocks)
    short8 wu[8][4];
#pragma unroll
    for (int nt = 0; nt < 8; ++nt)
#pragma unroll
        for (int kk = 0; kk < 4; ++kk)
            wu[nt][kk] = fragG[nt * 256 + kk * 64 + lane];

    if (t < D) {
        gl[0][t] = We[t] * LOG2E;
        gl[1][t] = cIb[(size_t)g * D + t];
        gl[2][t] = cVb[(size_t)g * D + t];
    }
    __syncthreads();

    int s = (g == 0) ? 0 : (lastn[g - 1] + 1);
    int n = lastn[g] + 1 - s;                     // >= 1
    int ch = (n + 15) >> 4;
    int total = 2 * ch;
    int Q4 = (lane >> 4) << 2;                    // quarter's h-offset

    float* rb = &stage[w][0];
    const char* rbc = (const char*)rb;

    // per-lane address constants
    int loff[8];                    // global float-offset per staging load
#pragma unroll
    for (int i = 0; i < 8; ++i) {
        int row = (i << 1) + (lane >> 5);
        loff[i] = (row << 7) + (((lane & 31) ^ (row & 7)) << 2);
    }
    int arow = lane & 15;
    int swz = (arow & 7) << 4;
    int ab0 = ((arow << 9) + ((lane >> 4) << 5)) ^ swz;
    int ab1 = ((arow << 9) + ((lane >> 4) << 5) + 16) ^ swz;

    // issue 8 global_load_lds for chunk cc into this wave's stage buffer
    auto issue = [&](int cc) {
        int hf = (cc >= ch) ? 1 : 0;
        const float* sp = (hf ? xV : xI) + ((size_t)s << 7);
        int bb = (cc - hf * ch) << 4;
        if (bb + 16 <= n) {            // interior: no clamps
            const float* pb = sp + ((size_t)bb << 7);
#pragma unroll
            for (int i = 0; i < 8; ++i)
                gld16(pb + loff[i], rb + (i << 8) + (lane << 2));
        } else {                       // tail: clamp rows (weight-masked)
#pragma unroll
            for (int i = 0; i < 8; ++i) {
                int row = (i << 1) + (lane >> 5);
                int rr = bb + row; if (rr > n - 1) rr = n - 1;
                int lu = (lane & 31) ^ (row & 7);
                gld16(sp + ((size_t)rr << 7) + (lu << 2),
                      rb + (i << 8) + (lane << 2));
            }
        }
    };

    if (w < total) issue(w);

    float lIs = 0.f, lVs = 0.f;                   // 4x-duplicated sums
    float aI0 = 0.f, aI1 = 0.f, aV0 = 0.f, aV1 = 0.f;

    for (int c = w; c < total; c += 4) {
        int hf = (c >= ch) ? 1 : 0;
        int base = (c - hf * ch) << 4;

        asm volatile("s_waitcnt vmcnt(0)" ::: "memory");   // stage c landed
        __builtin_amdgcn_sched_barrier(0);

        // ---- row fragments (B-operand) from stage: row = lane&15 ----
        short8 af[4];
#pragma unroll
        for (int kk = 0; kk < 4; ++kk) {
            float4 f0 = *(const float4*)(rbc + ab0 + (kk << 7));
            float4 f1 = *(const float4*)(rbc + ab1 + (kk << 7));
            union { unsigned u[4]; short8 s8; } cv;
            cv.u[0] = packbf(f0.x, f0.y);
            cv.u[1] = packbf(f0.z, f0.w);
            cv.u[2] = packbf(f1.x, f1.y);
            cv.u[3] = packbf(f1.z, f1.w);
            af[kk] = cv.s8;
        }
        // ---- accumulate operands (dims 2*lane, 2*lane+1) from stage ----
        float2 fr[16];
#pragma unroll
        for (int r = 0; r < 16; ++r)
            fr[r] = *(const float2*)(rbc + ((((r << 9) + (lane << 3)))
                                           ^ ((r & 7) << 4)));
        asm volatile("s_waitcnt lgkmcnt(0)" ::: "memory"); // stage free
        __builtin_amdgcn_sched_barrier(0);
        if (c + 4 < total) issue(c + 4);   // hides under compute below

        // ---- swapped MFMA + epilogue: lane-local scalar e-partials ----
        float pI = 0.f, pV = 0.f;
#pragma unroll
        for (int nt = 0; nt < 8; ++nt) {
            f32x4 dacc = {0.f, 0.f, 0.f, 0.f};
#pragma unroll
            for (int kk = 0; kk < 4; ++kk)
                dacc = __builtin_amdgcn_mfma_f32_16x16x32_bf16(
                    wu[nt][kk], af[kk], dacc, 0, 0, 0);
            float4 we4 = *(const float4*)&gl[0][nt * 16 + Q4];
            float4 ci4 = *(const float4*)&gl[1][nt * 16 + Q4];
            float4 cv4 = *(const float4*)&gl[2][nt * 16 + Q4];
#pragma unroll
            for (int q = 0; q < 4; ++q) {
                float t2 = __builtin_amdgcn_exp2f(-dacc[q]);
                float dI = fmaf(t2, (&ci4.x)[q], 1.f);
                float dV = fmaf(t2, (&cv4.x)[q], 1.f);
                float rr = __builtin_amdgcn_rcpf(dI * dV);
                pI = fmaf((&we4.x)[q], dV * rr, pI);   // We/dI
                pV = fmaf((&we4.x)[q], dI * rr, pV);   // We/dV
            }
        }

        // ---- finish e[r]: sum the 4 lane-quarters; weights = 2^e ----
        pI += __shfl_xor(pI, 16); pI += __shfl_xor(pI, 32);
        pV += __shfl_xor(pV, 16); pV += __shfl_xor(pV, 32);
        bool valid = base + (lane & 15) < n;
        float wI = valid ? __builtin_amdgcn_exp2f(pI) : 0.f;
        float wV = valid ? __builtin_amdgcn_exp2f(pV) : 0.f;
        lIs += wI; lVs += wV;                      // x4 dup, corrected later

        // publish weights (lane r owns row base+r; same-wave DS ordering)
        if (lane < 16) { float2 wv2 = {wI, wV}; *(float2*)&wt[w][lane][0] = wv2; }

        // ---- weighted accumulate (pure fma chains) ----
#pragma unroll
        for (int r = 0; r < 16; ++r) {
            float2 f = fr[r];
            float2 wv = *(const float2*)&wt[w][r][0];
            aI0 = fmaf(wv.x, f.x, aI0); aI1 = fmaf(wv.x, f.y, aI1);
            aV0 = fmaf(wv.y, f.x, aV0); aV1 = fmaf(wv.y, f.y, aV1);
        }
    }

    // wave-reduce the duplicated l-sums (once per graph)
#pragma unroll
    for (int off = 1; off < 64; off <<= 1) {
        lIs += __shfl_xor(lIs, off);
        lVs += __shfl_xor(lVs, off);
    }

    // ---- cross-wave combine: plain sums; l carries a 4x dup factor ----
    {
        float2 vI = {aI0, aI1}, vV = {aV0, aV1};
        *(float2*)&cmbA[0][w][lane * 2] = vI;
        *(float2*)&cmbA[1][w][lane * 2] = vV;
    }
    if (lane == 0) { cmbL[0][w] = lIs; cmbL[1][w] = lVs; }
    __syncthreads();
    {
        int st = t >> 7, d = t & 127;
        float Ls = (cmbL[st][0] + cmbL[st][1]) + (cmbL[st][2] + cmbL[st][3]);
        float A  = (cmbA[st][0][d] + cmbA[st][1][d]) +
                   (cmbA[st][2][d] + cmbA[st][3][d]);
        // true l = Ls/4  ->  out = A / (Ls*0.25)
        out[(size_t)st * B * D + (size_t)g * D + d] =
            A * __builtin_amdgcn_rcpf(Ls * 0.25f);
    }
}

// ---------------------------------------------------------------------------
extern "C" void kernel_launch(void* const* d_in, const int* in_sizes, int n_in,
                              void* d_out, int out_size, void* d_ws, size_t ws_size,
                              hipStream_t stream) {
    const float* xI    = (const float*)d_in[0];
    const float* xV    = (const float*)d_in[1];
    const float* Wu    = (const float*)d_in[2];
    const float* bu    = (const float*)d_in[3];
    const float* Wv    = (const float*)d_in[4];
    const float* We    = (const float*)d_in[5];
    // d_in[6] = seg_ids (unused: segments contiguous, last_nodes suffices)
    const int*   lastn = (const int*)d_in[7];
    const int B = in_sizes[7];               // 8192

    float*  cIb   = (float*)d_ws;
    float*  cVb   = cIb + (size_t)B * D;
    short8* fragW = (short8*)(cVb + (size_t)B * D);

    pack_wu<<<8, 256, 0, stream>>>(Wu, fragW);
    gate_k<<<(B + 15) / 16, 256, 0, stream>>>(xI, xV, Wv, bu, lastn, cIb, cVb, B);
    attn_main<<<B, 256, 0, stream>>>(xI, xV, We, lastn, cIb, cVb, fragW,
                                     (float*)d_out, B);
}

// Round 15
// 297.387 us; speedup vs baseline: 2.0105x; 2.0105x over previous
//
#include <hip/hip_runtime.h>
#include <stdint.h>

typedef short short8 __attribute__((ext_vector_type(8)));
typedef float f32x4 __attribute__((ext_vector_type(4)));

#define D 128
#define LOG2E 1.44269504088896340736f

__device__ __forceinline__ unsigned short f2bf(float f) {
    union { float f; unsigned u; } v; v.f = f;
    unsigned u = v.u;
    unsigned r = (u + 0x7FFFu + ((u >> 16) & 1u)) >> 16;  // RNE
    return (unsigned short)r;
}

// pack two f32 -> one u32 of two bf16 (round-half-up via +0x8000, then v_perm)
__device__ __forceinline__ unsigned packbf(float x, float y) {
    unsigned ux = __float_as_uint(x) + 0x8000u;
    unsigned uy = __float_as_uint(y) + 0x8000u;
    return __builtin_amdgcn_perm(uy, ux, 0x07060302u);
}

// HBM -> LDS direct (16B per lane). LDS dest must be linear base + lane*16.
__device__ __forceinline__ void gld16(const float* g, float* l) {
    __builtin_amdgcn_global_load_lds(
        (const __attribute__((address_space(1))) void*)g,
        (__attribute__((address_space(3))) void*)l, 16, 0, 0);
}

// ---------------------------------------------------------------------------
// Kernel 1: pre-pack (Wu * log2e) as bf16 MFMA fragments (A/B layout is
// lane-identical): t = nt*256 + kk*64 + lane holds
// Wu[nt*16+(lane&15)][kk*32+(lane>>4)*8+j] * log2e.
// ---------------------------------------------------------------------------
__global__ __launch_bounds__(256) void pack_wu(const float* __restrict__ Wu,
                                               short8* __restrict__ frag) {
    int tid = blockIdx.x * 256 + threadIdx.x;
    int nt = tid >> 8, kk = (tid >> 6) & 3, l = tid & 63;
    int col = nt * 16 + (l & 15);
    int kb  = kk * 32 + ((l >> 4) * 8);
    short8 o;
#pragma unroll
    for (int j = 0; j < 8; ++j) o[j] = (short)f2bf(Wu[col * D + kb + j] * LOG2E);
    frag[tid] = o;
}

// ---------------------------------------------------------------------------
// Kernel 2: per-graph gate factors  c = 2^{-(Wv·x_last + bu)·log2e}. (verified)
// ---------------------------------------------------------------------------
__global__ __launch_bounds__(256) void gate_k(const float* __restrict__ xI,
                                              const float* __restrict__ xV,
                                              const float* __restrict__ Wv,
                                              const float* __restrict__ bu,
                                              const int* __restrict__ lastn,
                                              float* __restrict__ cIb,
                                              float* __restrict__ cVb, int B) {
    __shared__ __align__(16) float xs[4][2][D];
    int t = threadIdx.x, h = t & 127, st = t >> 7;
    float bias = bu[h];
    const float4* wv4 = (const float4*)(Wv + (size_t)h * D);
    const float* src = st ? xV : xI;
    float* dst = st ? cVb : cIb;
    int g0 = blockIdx.x * 16;
    for (int p = 0; p < 4; ++p) {
        int gb = g0 + p * 4;
#pragma unroll
        for (int j = 0; j < 4; ++j) {
            int gg = gb + j; if (gg >= B) gg = B - 1;
            xs[j][st][h] = src[(size_t)lastn[gg] * D + h];
        }
        __syncthreads();
        const float4* x0 = (const float4*)xs[0][st];
        const float4* x1 = (const float4*)xs[1][st];
        const float4* x2 = (const float4*)xs[2][st];
        const float4* x3 = (const float4*)xs[3][st];
        float a0 = 0.f, a1 = 0.f, a2 = 0.f, a3 = 0.f;
#pragma unroll
        for (int i = 0; i < 32; ++i) {
            float4 w = wv4[i], b;
            b = x0[i]; a0 += w.x*b.x + w.y*b.y + w.z*b.z + w.w*b.w;
            b = x1[i]; a1 += w.x*b.x + w.y*b.y + w.z*b.z + w.w*b.w;
            b = x2[i]; a2 += w.x*b.x + w.y*b.y + w.z*b.z + w.w*b.w;
            b = x3[i]; a3 += w.x*b.x + w.y*b.y + w.z*b.z + w.w*b.w;
        }
        if (gb + 0 < B) dst[(size_t)(gb+0)*D + h] = __builtin_amdgcn_exp2f(-(a0+bias)*LOG2E);
        if (gb + 1 < B) dst[(size_t)(gb+1)*D + h] = __builtin_amdgcn_exp2f(-(a1+bias)*LOG2E);
        if (gb + 2 < B) dst[(size_t)(gb+2)*D + h] = __builtin_amdgcn_exp2f(-(a2+bias)*LOG2E);
        if (gb + 3 < B) dst[(size_t)(gb+3)*D + h] = __builtin_amdgcn_exp2f(-(a3+bias)*LOG2E);
        __syncthreads();
    }
}

// ---------------------------------------------------------------------------
// Kernel 3: fused main = gld16 staging pipeline (r4) x wu-in-VGPR swapped
// MFMA (r13). Block per graph, 4 waves striding 16-row chunks. No LDS bfrag
// (Wu lives in 64 statically-indexed VGPRs/wave); rows staged HBM->LDS via
// global_load_lds (zero gather VGPRs, pre-swizzled source); per chunk:
//   vmcnt(0) -> af (swizzled b128) + fr (float2) from LDS -> lgkmcnt(0) ->
//   issue next chunk's gld16 (hidden under compute) -> swapped MFMA ->
//   scalar-e epilogue -> weights 2^e (no max, r9 bound) -> accumulate.
// LDS ~39 KB -> 4 blocks/CU. PLAIN launch_bounds(256): any min-waves hint
// throttles VGPR to 84 and spills (measured r2/r3/r10/r12/r14).
// ---------------------------------------------------------------------------
__global__ __launch_bounds__(256) void attn_main(
    const float* __restrict__ xI, const float* __restrict__ xV,
    const float* __restrict__ We, const int* __restrict__ lastn,
    const float* __restrict__ cIb, const float* __restrict__ cVb,
    const short8* __restrict__ fragG, float* __restrict__ out, int B) {
    __shared__ __align__(16) float stage[4][2048];   // 32 KB row staging
    __shared__ __align__(16) float gl[3][D];         // We*log2e, cI, cV
    __shared__ __align__(16) float wt[4][16][2];     // per-wave weights
    __shared__ float cmbA[2][4][D];                  // combine (plain sums)
    __shared__ float cmbL[2][4];

    int t = threadIdx.x, lane = t & 63, w = t >> 6;
    int g = blockIdx.x;

    // Wu fragments -> 64 VGPRs (statically indexed; L2-hot for all blocks)
    short8 wu[8][4];
#pragma unroll
    for (int nt = 0; nt < 8; ++nt)
#pragma unroll
        for (int kk = 0; kk < 4; ++kk)
            wu[nt][kk] = fragG[nt * 256 + kk * 64 + lane];

    if (t < D) {
        gl[0][t] = We[t] * LOG2E;
        gl[1][t] = cIb[(size_t)g * D + t];
        gl[2][t] = cVb[(size_t)g * D + t];
    }
    __syncthreads();

    int s = (g == 0) ? 0 : (lastn[g - 1] + 1);
    int n = lastn[g] + 1 - s;                     // >= 1
    int ch = (n + 15) >> 4;
    int total = 2 * ch;
    int Q4 = (lane >> 4) << 2;                    // quarter's h-offset

    float* rb = &stage[w][0];
    const char* rbc = (const char*)rb;

    // per-lane address constants
    int loff[8];                    // global float-offset per staging load
#pragma unroll
    for (int i = 0; i < 8; ++i) {
        int row = (i << 1) + (lane >> 5);
        loff[i] = (row << 7) + (((lane & 31) ^ (row & 7)) << 2);
    }
    int arow = lane & 15;
    int swz = (arow & 7) << 4;
    int ab0 = ((arow << 9) + ((lane >> 4) << 5)) ^ swz;
    int ab1 = ((arow << 9) + ((lane >> 4) << 5) + 16) ^ swz;

    // issue 8 global_load_lds for chunk cc into this wave's stage buffer
    auto issue = [&](int cc) {
        int hf = (cc >= ch) ? 1 : 0;
        const float* sp = (hf ? xV : xI) + ((size_t)s << 7);
        int bb = (cc - hf * ch) << 4;
        if (bb + 16 <= n) {            // interior: no clamps
            const float* pb = sp + ((size_t)bb << 7);
#pragma unroll
            for (int i = 0; i < 8; ++i)
                gld16(pb + loff[i], rb + (i << 8) + (lane << 2));
        } else {                       // tail: clamp rows (weight-masked)
#pragma unroll
            for (int i = 0; i < 8; ++i) {
                int row = (i << 1) + (lane >> 5);
                int rr = bb + row; if (rr > n - 1) rr = n - 1;
                int lu = (lane & 31) ^ (row & 7);
                gld16(sp + ((size_t)rr << 7) + (lu << 2),
                      rb + (i << 8) + (lane << 2));
            }
        }
    };

    if (w < total) issue(w);

    float lIs = 0.f, lVs = 0.f;                   // 4x-duplicated sums
    float aI0 = 0.f, aI1 = 0.f, aV0 = 0.f, aV1 = 0.f;

    for (int c = w; c < total; c += 4) {
        int hf = (c >= ch) ? 1 : 0;
        int base = (c - hf * ch) << 4;

        asm volatile("s_waitcnt vmcnt(0)" ::: "memory");   // stage c landed
        __builtin_amdgcn_sched_barrier(0);

        // ---- row fragments (B-operand) from stage: row = lane&15 ----
        short8 af[4];
#pragma unroll
        for (int kk = 0; kk < 4; ++kk) {
            float4 f0 = *(const float4*)(rbc + ab0 + (kk << 7));
            float4 f1 = *(const float4*)(rbc + ab1 + (kk << 7));
            union { unsigned u[4]; short8 s8; } cv;
            cv.u[0] = packbf(f0.x, f0.y);
            cv.u[1] = packbf(f0.z, f0.w);
            cv.u[2] = packbf(f1.x, f1.y);
            cv.u[3] = packbf(f1.z, f1.w);
            af[kk] = cv.s8;
        }
        // ---- accumulate operands (dims 2*lane, 2*lane+1) from stage ----
        float2 fr[16];
#pragma unroll
        for (int r = 0; r < 16; ++r)
            fr[r] = *(const float2*)(rbc + ((((r << 9) + (lane << 3)))
                                           ^ ((r & 7) << 4)));
        asm volatile("s_waitcnt lgkmcnt(0)" ::: "memory"); // stage free
        __builtin_amdgcn_sched_barrier(0);
        if (c + 4 < total) issue(c + 4);   // hides under compute below

        // ---- swapped MFMA + epilogue: lane-local scalar e-partials ----
        float pI = 0.f, pV = 0.f;
#pragma unroll
        for (int nt = 0; nt < 8; ++nt) {
            f32x4 dacc = {0.f, 0.f, 0.f, 0.f};
#pragma unroll
            for (int kk = 0; kk < 4; ++kk)
                dacc = __builtin_amdgcn_mfma_f32_16x16x32_bf16(
                    wu[nt][kk], af[kk], dacc, 0, 0, 0);
            float4 we4 = *(const float4*)&gl[0][nt * 16 + Q4];
            float4 ci4 = *(const float4*)&gl[1][nt * 16 + Q4];
            float4 cv4 = *(const float4*)&gl[2][nt * 16 + Q4];
#pragma unroll
            for (int q = 0; q < 4; ++q) {
                float t2 = __builtin_amdgcn_exp2f(-dacc[q]);
                float dI = fmaf(t2, (&ci4.x)[q], 1.f);
                float dV = fmaf(t2, (&cv4.x)[q], 1.f);
                float rr = __builtin_amdgcn_rcpf(dI * dV);
                pI = fmaf((&we4.x)[q], dV * rr, pI);   // We/dI
                pV = fmaf((&we4.x)[q], dI * rr, pV);   // We/dV
            }
        }

        // ---- finish e[r]: sum the 4 lane-quarters; weights = 2^e ----
        pI += __shfl_xor(pI, 16); pI += __shfl_xor(pI, 32);
        pV += __shfl_xor(pV, 16); pV += __shfl_xor(pV, 32);
        bool valid = base + (lane & 15) < n;
        float wI = valid ? __builtin_amdgcn_exp2f(pI) : 0.f;
        float wV = valid ? __builtin_amdgcn_exp2f(pV) : 0.f;
        lIs += wI; lVs += wV;                      // x4 dup, corrected later

        // publish weights (lane r owns row base+r; same-wave DS ordering)
        if (lane < 16) { float2 wv2 = {wI, wV}; *(float2*)&wt[w][lane][0] = wv2; }

        // ---- weighted accumulate (pure fma chains) ----
#pragma unroll
        for (int r = 0; r < 16; ++r) {
            float2 f = fr[r];
            float2 wv = *(const float2*)&wt[w][r][0];
            aI0 = fmaf(wv.x, f.x, aI0); aI1 = fmaf(wv.x, f.y, aI1);
            aV0 = fmaf(wv.y, f.x, aV0); aV1 = fmaf(wv.y, f.y, aV1);
        }
    }

    // wave-reduce the duplicated l-sums (once per graph)
#pragma unroll
    for (int off = 1; off < 64; off <<= 1) {
        lIs += __shfl_xor(lIs, off);
        lVs += __shfl_xor(lVs, off);
    }

    // ---- cross-wave combine: plain sums; l carries a 4x dup factor ----
    {
        float2 vI = {aI0, aI1}, vV = {aV0, aV1};
        *(float2*)&cmbA[0][w][lane * 2] = vI;
        *(float2*)&cmbA[1][w][lane * 2] = vV;
    }
    if (lane == 0) { cmbL[0][w] = lIs; cmbL[1][w] = lVs; }
    __syncthreads();
    {
        int st = t >> 7, d = t & 127;
        float Ls = (cmbL[st][0] + cmbL[st][1]) + (cmbL[st][2] + cmbL[st][3]);
        float A  = (cmbA[st][0][d] + cmbA[st][1][d]) +
                   (cmbA[st][2][d] + cmbA[st][3][d]);
        // true l = Ls/4  ->  out = A / (Ls*0.25)
        out[(size_t)st * B * D + (size_t)g * D + d] =
            A * __builtin_amdgcn_rcpf(Ls * 0.25f);
    }
}

// ---------------------------------------------------------------------------
extern "C" void kernel_launch(void* const* d_in, const int* in_sizes, int n_in,
                              void* d_out, int out_size, void* d_ws, size_t ws_size,
                              hipStream_t stream) {
    const float* xI    = (const float*)d_in[0];
    const float* xV    = (const float*)d_in[1];
    const float* Wu    = (const float*)d_in[2];
    const float* bu    = (const float*)d_in[3];
    const float* Wv    = (const float*)d_in[4];
    const float* We    = (const float*)d_in[5];
    // d_in[6] = seg_ids (unused: segments contiguous, last_nodes suffices)
    const int*   lastn = (const int*)d_in[7];
    const int B = in_sizes[7];               // 8192

    float*  cIb   = (float*)d_ws;
    float*  cVb   = cIb + (size_t)B * D;
    short8* fragW = (short8*)(cVb + (size_t)B * D);

    pack_wu<<<8, 256, 0, stream>>>(Wu, fragW);
    gate_k<<<(B + 15) / 16, 256, 0, stream>>>(xI, xV, Wv, bu, lastn, cIb, cVb, B);
    attn_main<<<B, 256, 0, stream>>>(xI, xV, We, lastn, cIb, cVb, fragW,
                                     (float*)d_out, B);
}